// Round 12
// baseline (24.103 us; speedup 1.0000x reference)
//
#include <hip/hip_runtime.h>

// Not-a-knot cubic spline upsample (512 x 8192 f32 -> 512 x 32768 f32).
//
// R11 structure (2048 blocks x 4 pipelined tiles, packed f32x4 coeffs) plus:
//  - ys skewed at f32x4-slot granularity (slot -> slot + slot/8): conv's
//    16B-lane-stride ds_read_b128 was an ~8-way bank conflict (lanes i,i+8,..
//    share banks); skew spreads them. Cc already had the same skew.
//  - conv via 2 Green-conv seeds (K=8) + 3 recurrences M[j+-1]=d-4M-M'
//    (R10-validated: err <= 4e-3 << 0.103): 46 fma vs 85, window 20 floats
//    (5 b128, was 6).
//  - eval: u=0 and u=3 are select-free (crossing is monotone; h=0's u0
//    "miss" evaluates the degenerate interval at t=1 = exact y[0]).
// Boundary tiles (0,15): reflected-RHS b-space conv (R1-proven), K=10.

typedef float f32x4 __attribute__((ext_vector_type(4)));

constexpr int W    = 8192;
constexpr int WU   = 32768;
constexpr int TILE = 512;
constexpr int TPB  = 4;
constexpr int HL   = 16;
constexpr int YSL  = 153;            // skewed f32x4 slots (136 + 17)
constexpr int CN   = 513;            // intervals s0-1 .. s0+511
constexpr int CCN  = 578;            // skewed Cc slots
constexpr int KB   = 10;
constexpr int BTN  = 538;
constexpr int MTN  = 520;

constexpr float Rr  = -0.26794919243112270647f;  // sqrt(3)-2
constexpr float W0c = -4.39230484541326386f;     // 12C(r-1)
constexpr float W1c =  2.78460969082652752f;     // 6C(1-r)^2
constexpr float Cg  =  0.288675134594812882f;    // C = 1/(2 sqrt(3))

__device__ __forceinline__ int skw(int s) { return s + (s >> 3); }

__global__ __launch_bounds__(256)
void spline_kernel(const float* __restrict__ x, float* __restrict__ out)
{
    const int row = blockIdx.y;
    const int t0  = blockIdx.x * TPB;
    const int tid = threadIdx.x;
    const int n   = W - 4;

    const float* __restrict__ xr   = x   + (size_t)row * W;
    float*       __restrict__ orow = out + (size_t)row * WU;

    __shared__ __align__(16) f32x4 ys4[2][YSL];
    __shared__ __align__(16) f32x4 Cc[CCN];
    __shared__ float bt[BTN];
    __shared__ float Mtmp[MTN];

    // skew-aware scalar view: float index i of the UNSKEWED layout
    auto ysAt = [](const float* p, int i) -> float {
        return p[i + ((i >> 5) << 2)];
    };

    auto LOAD = [&](int tile) -> f32x4 {
        f32x4 v = {0.f, 0.f, 0.f, 0.f};
        if (tid < 136) {
            int base = tile * TILE - HL + 4 * tid;
            if (tile == 0 || tile == 15) {
                #pragma unroll
                for (int e = 0; e < 4; ++e) {
                    int g = base + e;
                    g = g < 0 ? 0 : (g > W - 1 ? W - 1 : g);
                    v[e] = xr[g];
                }
            } else {
                v = *(const f32x4*)(xr + base);
            }
        }
        return v;
    };

    f32x4 regA = LOAD(t0);
    if (tid < 136) ys4[0][skw(tid)] = regA;
    __syncthreads();
    regA = LOAD(t0 + 1);

    int cur = 0;
    for (int k = 0; k < TPB; ++k) {
        const int tile = t0 + k;
        const int s0   = tile * TILE;

        f32x4 regB = {0.f, 0.f, 0.f, 0.f};
        if (k + 2 < TPB) regB = LOAD(t0 + k + 2);

        const f32x4* ys4c = ys4[cur];
        const float* ysf  = (const float*)ys4c;
        const bool boundary = (tile == 0) || (tile == 15);

        if (!boundary) {
            // ---- interior conv: seeds + recurrence, skewed b128 reads ----
            if (tid < 129) {
                float w[20];                     // w[m] = y-float-idx 4*tid+8+m
                #pragma unroll
                for (int kk = 0; kk < 5; ++kk) {
                    f32x4 v = ys4c[skw(tid + 2 + kk)];
                    w[4*kk+0]=v.x; w[4*kk+1]=v.y; w[4*kk+2]=v.z; w[4*kk+3]=v.w;
                }
                // seeds: M at knots s0-1+4t+1 (m=8), s0-1+4t+2 (m=9), K=8
                float m1 = W0c * w[8], m2 = W0c * w[9];
                float wd = W1c;
                #pragma unroll
                for (int d = 1; d <= 8; ++d) {
                    m1 += wd * (w[8 - d] + w[8 + d]);
                    m2 += wd * (w[9 - d] + w[9 + d]);
                    wd *= Rr;                    // folds to literals
                }
                float a[5];                      // M at knots s0-1+4t+d
                a[1] = m1; a[2] = m2;
                a[0] = 6.f*(w[9]  - 2.f*w[8]  + w[7]) - 4.f*m1   - m2;
                a[3] = 6.f*(w[10] - 2.f*w[9]  + w[8]) - 4.f*m2   - m1;
                a[4] = 6.f*(w[11] - 2.f*w[10] + w[9]) - 4.f*a[3] - m2;
                const int nc = (tid == 128) ? 1 : 4;
                #pragma unroll
                for (int c = 0; c < 4; ++c) {
                    if (c < nc) {
                        float y0 = w[7 + c], y1 = w[8 + c];
                        f32x4 cc = {y0,
                                    (y1 - y0) - (2.f*a[c] + a[c+1]) * (1.f/6.f),
                                    0.5f * a[c],
                                    (a[c+1] - a[c]) * (1.f/6.f)};
                        Cc[skw(4 * tid + c)] = cc;
                    }
                }
            }
        } else {
            // ---- boundary: reflected-RHS M (R1-proven), then coeffs ----
            const int YS0 = s0 - HL;
            auto Dp = [&](int p) -> float {
                int a2 = p - YS0;
                return 6.0f * (ysAt(ysf,a2+1) - 2.0f*ysAt(ysf,a2) + ysAt(ysf,a2-1));
            };
            auto M1v = [&]() -> float {
                int a2 = -YS0;
                return ysAt(ysf,a2) - 2.f*ysAt(ysf,a2+1) + ysAt(ysf,a2+2);
            };
            auto Mn2v = [&]() -> float {
                int a2 = (W-1) - YS0;
                return ysAt(ysf,a2) - 2.f*ysAt(ysf,a2-1) + ysAt(ysf,a2-2);
            };
            auto bval = [&](int m) -> float {
                if (m == -1 || m == n) return 0.f;
                float sgn = 1.f;
                if (m < -1)     { m = -2 - m;    sgn = -1.f; }
                else if (m > n) { m = 2*n - m;   sgn = -1.f; }
                float v = Dp(m + 2);
                if (m == 0)     v -= M1v();
                if (m == n - 1) v -= Mn2v();
                return sgn * v;
            };
            const int BT0 = s0 - 3 - KB;
            for (int idx = tid; idx < BTN; idx += 256)
                bt[idx] = bval(BT0 + idx);
            __syncthreads();
            auto convb = [&](int j) -> float {
                int base = j - 2 - BT0;
                float acc = Cg * bt[base];
                float wr  = Cg;
                #pragma unroll
                for (int d = 1; d <= KB; ++d) {
                    wr  *= Rr;
                    acc += wr * (bt[base-d] + bt[base+d]);
                }
                return acc;
            };
            for (int idx = tid; idx < 514; idx += 256) {
                int j = s0 - 1 + idx;
                j = j < 0 ? 0 : (j > W-1 ? W-1 : j);
                float m;
                if (j == 0)        m = 2.f*M1v()  - convb(2);
                else if (j == 1)   m = M1v();
                else if (j == W-2) m = Mn2v();
                else if (j == W-1) m = 2.f*Mn2v() - convb(W-3);
                else               m = convb(j);
                Mtmp[idx] = m;
            }
            __syncthreads();
            for (int idx = tid; idx < CN; idx += 256) {
                float y0 = ysAt(ysf, idx + 15), y1 = ysAt(ysf, idx + 16);
                float m0 = Mtmp[idx], m1 = Mtmp[idx + 1];
                f32x4 cc = {y0,
                            (y1 - y0) - (2.f*m0 + m1) * (1.f/6.f),
                            0.5f * m0,
                            (m1 - m0) * (1.f/6.f)};
                Cc[skw(idx)] = cc;
            }
        }
        __syncthreads();                          // coeffs ready; ys[cur] free

        // ---- stage next tile's y into the other buffer (drains under eval)
        if (k + 1 < TPB) {
            if (tid < 136) ys4[cur ^ 1][skw(tid)] = regA;
        }

        // ---- eval: select-free u0/u3; 2 x ds_read_b128 per 4 outputs ----
        constexpr float inv = 1.f / 32767.f;
        #pragma unroll
        for (int it = 0; it < 2; ++it) {
            const int j = tid + 256 * it;         // interval idx; q0 = 4h
            const int h = s0 + j;
            const int e = 32767 - 3 * h;
            f32x4 cA = Cc[skw(j)];
            f32x4 cB = Cc[skw(j + 1)];
            const int N1 = e + 8191, N2 = e + 16382;
            const bool c1 = N1 >= 32767, c2 = N2 >= 32767;
            float t0 = (float)e * inv;            // h=0: t0=1 on degenerate
            float t1 = (float)(c1 ? N1 - 32767 : N1) * inv;
            float t2 = (float)(c2 ? N2 - 32767 : N2) * inv;
            float t3 = (float)(e - 8194) * inv;   // u=3 always crosses
            f32x4 k1 = c1 ? cB : cA;
            f32x4 k2 = c2 ? cB : cA;
            float r0 = cA.x + t0 * (cA.y + t0 * (cA.z + t0 * cA.w));
            float r1 = k1.x + t1 * (k1.y + t1 * (k1.z + t1 * k1.w));
            float r2 = k2.x + t2 * (k2.y + t2 * (k2.z + t2 * k2.w));
            float r3 = cB.x + t3 * (cB.y + t3 * (cB.z + t3 * cB.w));
            *(f32x4*)(orow + 4 * h) = (f32x4){r0, r1, r2, r3};
        }
        __syncthreads();                          // Cc reads + ys writes done
        regA = regB;
        cur ^= 1;
    }
}

extern "C" void kernel_launch(void* const* d_in, const int* in_sizes, int n_in,
                              void* d_out, int out_size, void* d_ws, size_t ws_size,
                              hipStream_t stream) {
    const float* x = (const float*)d_in[0];
    float* out = (float*)d_out;
    const int B = in_sizes[0] / W;               // 512 rows
    dim3 grid(W / TILE / TPB, B), block(256);    // 2048 blocks
    hipLaunchKernelGGL(spline_kernel, grid, block, 0, stream, x, out);
}